// Round 6
// baseline (52.320 us; speedup 1.0000x reference)
//
#include <hip/hip_runtime.h>
#include <math.h>

#define NNODE 512
#define NBATCH 4
#define NFEAT 12
#define QKD 128
#define NVD 128
#define EVD 32
#define CATD 160          // NVD + EVD
#define TRD 256
#define NCLS 5
#define NROWS 2048        // NBATCH * NNODE
#define EPSV 1e-5f
#define NSTATBUF 8        // split BN-stat atomic contention 8 ways
#define NCHUNK 8          // j-chunks per row (flash split)
#define JC 64             // j-chunk width
#define RB 16             // rows per flashA block (MFMA M=16)
#define SSW 68            // sS row stride (f32): 4-dw bank step -> 2-way
#define KBW 136           // sKB row stride (ushort): 272B -> 2-way on frags
#define NVW 72            // sNV row stride (ushort): 144B -> 2-way on frags

typedef float floatx4 __attribute__((ext_vector_type(4)));
typedef __bf16 bf16x8 __attribute__((ext_vector_type(8)));
typedef unsigned short ushort_t;
typedef ushort_t ushort8 __attribute__((ext_vector_type(8)));
typedef ushort_t ushort4v __attribute__((ext_vector_type(4)));

// f32 -> bf16 bits, round-to-nearest-even
static __device__ __forceinline__ ushort_t f2bf(float x) {
  unsigned int u = __float_as_uint(x);
  return (ushort_t)((u + 0x7fffu + ((u >> 16) & 1u)) >> 16);
}
static __device__ __forceinline__ bf16x8 pack8(ushort4v lo, ushort4v hi) {
  ushort8 u;
  u[0] = lo.x; u[1] = lo.y; u[2] = lo.z; u[3] = lo.w;
  u[4] = hi.x; u[5] = hi.y; u[6] = hi.z; u[7] = hi.w;
  return __builtin_bit_cast(bf16x8, u);
}

// ---------------------------------------------------------------------------
// Kernel 1: projections -> bf16 Qb[row][d], Kb[row][d], NVT[b][d][j].
// 32 blocks x 256 thr, 64 rows/block. Blocks 0..15 zero BN stats.
// ---------------------------------------------------------------------------
__global__ __launch_bounds__(256) void qkv_kernel(
    const float* __restrict__ nodes,
    const float* __restrict__ Wq, const float* __restrict__ bq,
    const float* __restrict__ Wk, const float* __restrict__ bk,
    const float* __restrict__ Wnv, const float* __restrict__ bnv,
    ushort_t* __restrict__ Qb, ushort_t* __restrict__ Kb,
    ushort_t* __restrict__ NVT, float* __restrict__ stats) {
  const int tid = threadIdx.x;
  const int blk = blockIdx.x;           // 0..31
  const int rowbase = blk * 64;
  const int b = rowbase >> 9;
  const int jloc = rowbase & (NNODE - 1);
  if (blk < 2 * NSTATBUF) stats[blk * 256 + tid] = 0.f;   // 16x256 = 4096
  __shared__ float sn[64][NFEAT];
  for (int idx = tid; idx < 64 * NFEAT; idx += 256)
    ((float*)sn)[idx] = nodes[(size_t)rowbase * NFEAT + idx];
  __syncthreads();

  // ---- Q/K: thread owns d = tid&127; rows (tid>>7)*32 .. +31 ----------
  {
    const int d  = tid & 127;
    const int rg = tid >> 7;
    float wq[NFEAT], wk[NFEAT];
#pragma unroll
    for (int k = 0; k < NFEAT; ++k) {
      wq[k] = Wq[d * NFEAT + k];
      wk[k] = Wk[d * NFEAT + k];
    }
    const float bqv = bq[d], bkv = bk[d];
#pragma unroll 4
    for (int rr = 0; rr < 32; ++rr) {
      const int rl = rg * 32 + rr;
      float aq = bqv, ak = bkv;
#pragma unroll
      for (int k = 0; k < NFEAT; ++k) {
        const float n = sn[rl][k];
        aq = fmaf(n, wq[k], aq);
        ak = fmaf(n, wk[k], ak);
      }
      Qb[(size_t)(rowbase + rl) * QKD + d] = f2bf(aq);
      Kb[(size_t)(rowbase + rl) * QKD + d] = f2bf(ak);
    }
  }
  // ---- NV^T: thread owns d = tid>>1, half = tid&1 (32 j each) ----------
  {
    const int d    = tid >> 1;
    const int half = tid & 1;
    float wnv[NFEAT];
#pragma unroll
    for (int k = 0; k < NFEAT; ++k) wnv[k] = Wnv[d * NFEAT + k];
    const float bnvv = bnv[d];
    ushort8* dst = (ushort8*)(NVT + (size_t)b * QKD * NNODE +
                              (size_t)d * NNODE + jloc + half * 32);
#pragma unroll
    for (int t = 0; t < 4; ++t) {
      ushort8 v;
#pragma unroll
      for (int e = 0; e < 8; ++e) {
        const int rl = half * 32 + t * 8 + e;
        float av = bnvv;
#pragma unroll
        for (int k = 0; k < NFEAT; ++k) av = fmaf(sn[rl][k], wnv[k], av);
        v[e] = f2bf(av);
      }
      dst[t] = v;
    }
  }
}

// ---------------------------------------------------------------------------
// Kernel 2: flashA via MFMA. Block = (batch, chunk of 64 j, 16 rows).
// Grid 4*8*32 = 1024, 256 thr (4 waves). Fragment layout (16x16x32 bf16):
//   A: lane l -> row=l&15, k = 4*(l>>4)+{0..3}, elems 4..7 at k+16
//   B: lane l -> col=l&15, same k pattern
//   C: lane l, reg r -> col=l&15, row=(l>>4)*4+r        [verified R5]
// ---------------------------------------------------------------------------
__global__ __launch_bounds__(256) void flashA_kernel(
    const ushort_t* __restrict__ Qb, const ushort_t* __restrict__ Kb,
    const ushort_t* __restrict__ NVT,
    const float* __restrict__ edges, const float* __restrict__ dist,
    const int* __restrict__ mask,
    float* __restrict__ pnv, float* __restrict__ pm,
    float* __restrict__ pl, float* __restrict__ pse) {
  __shared__ ushort_t uKV[QKD * NVW];   // union: sKB[64][136] / sNV[128][72]
  __shared__ __align__(16) float sS[RB][SSW];
  __shared__ float sM[RB], sL[RB], sSE[RB];

  const int tid = threadIdx.x;
  const int bid = blockIdx.x;           // 0..1023
  const int b   = bid >> 8;             // batch
  const int c   = (bid >> 5) & 7;       // j-chunk
  const int rg  = bid & 31;             // row group
  const int rowbase = b * NNODE + rg * RB;
  const int jbase   = c * JC;

  const int lane = tid & 63;
  const int wv   = tid >> 6;            // wave 0..3
  const int col  = lane & 15;
  const int kg   = lane >> 4;

  // ---- prefetch dist/mask (score positions) + edges (softmax rows) -----
  const int jl = wv * 16 + col;         // this thread's score column
  float dd[4]; int mm[4]; float ee[4];
#pragma unroll
  for (int r = 0; r < 4; ++r) {
    const size_t off = (size_t)(rowbase + kg * 4 + r) * NNODE + jbase + jl;
    dd[r] = dist[off];
    mm[r] = mask[off];
  }
#pragma unroll
  for (int rr = 0; rr < 4; ++rr)
    ee[rr] = edges[(size_t)(rowbase + 4 * wv + rr) * NNODE + jbase + lane];

  // ---- stage K chunk -> sKB[64][136] (coalesced ushort8) ----------------
  ushort_t* sKB = uKV;
  {
    const int j  = tid >> 2;            // 0..63
    const int d0 = (tid & 3) * 32;
    const ushort8* src =
        (const ushort8*)(Kb + (size_t)(b * NNODE + jbase + j) * QKD + d0);
    ushort8* dst = (ushort8*)(sKB + j * KBW + d0);
#pragma unroll
    for (int t = 0; t < 4; ++t) dst[t] = src[t];
  }
  // ---- Q A-fragments direct from global (bf16) --------------------------
  bf16x8 aq[4];
  {
    const ushort_t* Qr = Qb + (size_t)(rowbase + col) * QKD;
#pragma unroll
    for (int ks = 0; ks < 4; ++ks)
      aq[ks] = pack8(*(const ushort4v*)(Qr + ks * 32 + kg * 4),
                     *(const ushort4v*)(Qr + ks * 32 + 16 + kg * 4));
  }
  __syncthreads();

  // ---- QK^T: wave wv owns j-tile wv; 4 MFMAs ----------------------------
  floatx4 acc = {0.f, 0.f, 0.f, 0.f};
  {
    const ushort_t* kb = sKB + (size_t)(wv * 16 + col) * KBW;
#pragma unroll
    for (int ks = 0; ks < 4; ++ks) {
      const bf16x8 bf = pack8(*(const ushort4v*)(kb + ks * 32 + kg * 4),
                              *(const ushort4v*)(kb + ks * 32 + 16 + kg * 4));
      acc = __builtin_amdgcn_mfma_f32_16x16x32_bf16(aq[ks], bf, acc, 0, 0, 0);
    }
  }
  // ---- scores -> sS -----------------------------------------------------
  {
    const float coeff = 0.0883883476483184f;  // 1/sqrt(128)
#pragma unroll
    for (int r = 0; r < 4; ++r) {
      float s = acc[r] * coeff / (dd[r] + 1.0f);
      if (mm[r]) s = -__builtin_inff();
      sS[kg * 4 + r][jl] = s;
    }
  }
  __syncthreads();                      // scores visible; sKB reads done

  // ---- issue NV staging loads early (hide under softmax) ----------------
  const int dnv = tid >> 1, half = tid & 1;
  const ushort8* nsrc = (const ushort8*)(NVT + (size_t)b * QKD * NNODE +
                                         (size_t)dnv * NNODE + jbase + half * 32);
  const ushort8 nv0 = nsrc[0], nv1 = nsrc[1], nv2 = nsrc[2], nv3 = nsrc[3];

  // ---- softmax partials (wave wv -> rows 4wv..4wv+3) --------------------
#pragma unroll
  for (int rr = 0; rr < 4; ++rr) {
    const int r = 4 * wv + rr;
    const float v = sS[r][lane];
    float m = v;
#pragma unroll
    for (int s = 1; s < 64; s <<= 1) m = fmaxf(m, __shfl_xor(m, s, 64));
    const float w = (m > -__builtin_inff()) ? __expf(v - m) : 0.f;
    sS[r][lane] = w;
    float l = w, se = w * ee[rr];
#pragma unroll
    for (int s = 1; s < 64; s <<= 1) {
      l  += __shfl_xor(l, s, 64);
      se += __shfl_xor(se, s, 64);
    }
    if (lane == 0) { sM[r] = m; sL[r] = l; sSE[r] = se; }
  }
  // ---- write NV chunk into union buffer --------------------------------
  ushort_t* sNV = uKV;
  {
    ushort8* nd = (ushort8*)(sNV + dnv * NVW + half * 32);
    nd[0] = nv0; nd[1] = nv1; nd[2] = nv2; nd[3] = nv3;
  }
  __syncthreads();

  // ---- PV: pnv(16 x 128) = w(16 x 64j) @ NV(64j x 128d); 4 MFMAs/wave --
  bf16x8 aw[2];
#pragma unroll
  for (int ks = 0; ks < 2; ++ks) {
    const float4 lo = *(const float4*)&sS[col][ks * 32 + kg * 4];
    const float4 hi = *(const float4*)&sS[col][ks * 32 + 16 + kg * 4];
    ushort8 u;
    u[0] = f2bf(lo.x); u[1] = f2bf(lo.y); u[2] = f2bf(lo.z); u[3] = f2bf(lo.w);
    u[4] = f2bf(hi.x); u[5] = f2bf(hi.y); u[6] = f2bf(hi.z); u[7] = f2bf(hi.w);
    aw[ks] = __builtin_bit_cast(bf16x8, u);
  }
  floatx4 pv0 = {0.f, 0.f, 0.f, 0.f};
  floatx4 pv1 = {0.f, 0.f, 0.f, 0.f};
  {
    const int d0 = wv * 32 + col;
    const int d1 = wv * 32 + 16 + col;
    const ushort_t* n0 = sNV + (size_t)d0 * NVW;
    const ushort_t* n1 = sNV + (size_t)d1 * NVW;
#pragma unroll
    for (int ks = 0; ks < 2; ++ks) {
      const bf16x8 b0 = pack8(*(const ushort4v*)(n0 + ks * 32 + kg * 4),
                              *(const ushort4v*)(n0 + ks * 32 + 16 + kg * 4));
      const bf16x8 b1 = pack8(*(const ushort4v*)(n1 + ks * 32 + kg * 4),
                              *(const ushort4v*)(n1 + ks * 32 + 16 + kg * 4));
      pv0 = __builtin_amdgcn_mfma_f32_16x16x32_bf16(aw[ks], b0, pv0, 0, 0, 0);
      pv1 = __builtin_amdgcn_mfma_f32_16x16x32_bf16(aw[ks], b1, pv1, 0, 0, 0);
    }
  }
  // ---- write partials ---------------------------------------------------
#pragma unroll
  for (int r = 0; r < 4; ++r) {
    const size_t rowoff = ((size_t)c * NROWS + rowbase + kg * 4 + r) * NVD;
    pnv[rowoff + wv * 32 + col]      = pv0[r];
    pnv[rowoff + wv * 32 + 16 + col] = pv1[r];
  }
  if (tid < RB) {
    const int o = c * NROWS + rowbase + tid;
    pm[o] = sM[tid]; pl[o] = sL[tid]; pse[o] = sSE[tid];
  }
}

// ---------------------------------------------------------------------------
// Kernel 3: passB + transform fused. 512 blocks x 256 thr, 4 rows/block.
// ---------------------------------------------------------------------------
__global__ __launch_bounds__(256) void passBtrans_kernel(
    const float* __restrict__ pnv, const float* __restrict__ pm,
    const float* __restrict__ pl, const float* __restrict__ pse,
    const float* __restrict__ Wev, const float* __restrict__ bev,
    const float* __restrict__ Wt, const float* __restrict__ bt,
    float* __restrict__ vals, float* __restrict__ stats) {
  __shared__ __align__(16) float sC[4][CATD];     // 2.5 KB
  const int tid = threadIdx.x;
  const int bid = blockIdx.x;          // 0..511
  const int row0 = bid * 4;

#pragma unroll
  for (int k = 0; k < 2; ++k) {
    const int idx = tid + k * 256;
    const int r = idx >> 7, d = idx & 127;
    const int row = row0 + r;
    float mg = -__builtin_inff();
#pragma unroll
    for (int c = 0; c < NCHUNK; ++c) mg = fmaxf(mg, pm[c * NROWS + row]);
    float lg = 0.f, nv = 0.f;
#pragma unroll
    for (int c = 0; c < NCHUNK; ++c) {
      const float mc = pm[c * NROWS + row];
      if (mc > -__builtin_inff()) {
        const float sc = __expf(mc - mg);
        lg = fmaf(pl[c * NROWS + row], sc, lg);
        nv = fmaf(pnv[((size_t)c * NROWS + row) * NVD + d], sc, nv);
      }
    }
    const float inv = (lg > 0.f) ? 1.f / lg : 0.f;
    sC[r][d] = tanhf(nv * inv);
  }
  if (tid < 4 * EVD) {
    const int r = tid >> 5, de = tid & 31;
    const int row = row0 + r;
    float mg = -__builtin_inff();
#pragma unroll
    for (int c = 0; c < NCHUNK; ++c) mg = fmaxf(mg, pm[c * NROWS + row]);
    float lg = 0.f, seg = 0.f;
#pragma unroll
    for (int c = 0; c < NCHUNK; ++c) {
      const float mc = pm[c * NROWS + row];
      if (mc > -__builtin_inff()) {
        const float sc = __expf(mc - mg);
        lg  = fmaf(pl[c * NROWS + row], sc, lg);
        seg = fmaf(pse[c * NROWS + row], sc, seg);
      }
    }
    const float sw = (lg > 0.f) ? 1.f : 0.f;
    const float se = (lg > 0.f) ? seg / lg : 0.f;
    sC[r][NVD + de] = tanhf(fmaf(Wev[de], se, bev[de] * sw));
  }
  __syncthreads();

  const int o = tid;
  const float4* __restrict__ w4 = (const float4*)(Wt + (size_t)o * CATD);
  float acc[4] = {0.f, 0.f, 0.f, 0.f};
#pragma unroll 8
  for (int k4 = 0; k4 < CATD / 4; ++k4) {
    const float4 w = w4[k4];
#pragma unroll
    for (int r = 0; r < 4; ++r) {
      const float4 cc = ((const float4*)sC[r])[k4];
      acc[r] += cc.x * w.x + cc.y * w.y + cc.z * w.z + cc.w * w.w;
    }
  }
  const float bto = bt[o];
  float s1 = 0.f, s2 = 0.f;
#pragma unroll
  for (int r = 0; r < 4; ++r) {
    const float v2 = acc[r] + bto;
    vals[(size_t)(row0 + r) * TRD + o] = v2;
    s1 += v2;
    s2 = fmaf(v2, v2, s2);
  }
  float* sb = stats + (size_t)(bid & (NSTATBUF - 1)) * 2 * TRD;
  atomicAdd(&sb[o], s1);
  atomicAdd(&sb[TRD + o], s2);
}

// ---------------------------------------------------------------------------
// Kernel 4: fused BN-fold + classifier. 512 blocks x 256 thr, 4 rows/block.
// ---------------------------------------------------------------------------
__global__ __launch_bounds__(256) void outbn_kernel(
    const float* __restrict__ vals, const float* __restrict__ stats,
    const float* __restrict__ gamma, const float* __restrict__ beta,
    const float* __restrict__ Wc, const float* __restrict__ bc,
    float* __restrict__ out) {
  __shared__ float sW[NCLS][TRD];
  __shared__ float sb[NCLS];
  __shared__ float red[4][NCLS];
  const int tid = threadIdx.x;
  const int o = tid;                   // 0..255
  float s1 = 0.f, s2 = 0.f;
#pragma unroll
  for (int k = 0; k < NSTATBUF; ++k) {
    s1 += stats[k * 2 * TRD + o];
    s2 += stats[k * 2 * TRD + TRD + o];
  }
  const float invN = 1.0f / (float)NROWS;
  const float mu  = s1 * invN;
  const float var = s2 * invN - mu * mu;
  const float inv = 1.0f / sqrtf(var + EPSV);
  const float g = gamma[o] * inv;
  const float bterm = beta[o] - mu * g;
  float v[NCLS];
#pragma unroll
  for (int c = 0; c < NCLS; ++c) {
    const float wc = Wc[c * TRD + o];
    sW[c][o] = wc * g;
    v[c] = wc * bterm;
  }
#pragma unroll
  for (int s = 1; s < 64; s <<= 1) {
#pragma unroll
    for (int c = 0; c < NCLS; ++c) v[c] += __shfl_xor(v[c], s, 64);
  }
  if ((tid & 63) == 0) {
#pragma unroll
    for (int c = 0; c < NCLS; ++c) red[tid >> 6][c] = v[c];
  }
  __syncthreads();
  if (tid < NCLS)
    sb[tid] = bc[tid] + red[0][tid] + red[1][tid] + red[2][tid] + red[3][tid];
  __syncthreads();

  const int lane = tid & 63;
  const int row = blockIdx.x * 4 + (tid >> 6);
  float vv[TRD / 64];
#pragma unroll
  for (int t = 0; t < TRD / 64; ++t)
    vv[t] = vals[(size_t)row * TRD + lane + 64 * t];
#pragma unroll
  for (int c = 0; c < NCLS; ++c) {
    float p = 0.f;
#pragma unroll
    for (int t = 0; t < TRD / 64; ++t)
      p = fmaf(vv[t], sW[c][lane + 64 * t], p);
#pragma unroll
    for (int s = 1; s < 64; s <<= 1) p += __shfl_xor(p, s, 64);
    if (lane == 0) out[(size_t)row * NCLS + c] = p + sb[c];
  }
}

// ---------------------------------------------------------------------------
extern "C" void kernel_launch(void* const* d_in, const int* in_sizes, int n_in,
                              void* d_out, int out_size, void* d_ws, size_t ws_size,
                              hipStream_t stream) {
  (void)in_sizes; (void)n_in; (void)out_size; (void)ws_size;
  const float* nodes = (const float*)d_in[0];
  const float* edges = (const float*)d_in[1];
  const float* dist  = (const float*)d_in[2];
  const int*   mask  = (const int*)d_in[3];
  const float* Wq  = (const float*)d_in[4];
  const float* bq  = (const float*)d_in[5];
  const float* Wk  = (const float*)d_in[6];
  const float* bk  = (const float*)d_in[7];
  const float* Wnv = (const float*)d_in[8];
  const float* bnv = (const float*)d_in[9];
  const float* Wev = (const float*)d_in[10];
  const float* bev = (const float*)d_in[11];
  const float* Wt  = (const float*)d_in[12];
  const float* bt  = (const float*)d_in[13];
  const float* gamma = (const float*)d_in[14];
  const float* beta  = (const float*)d_in[15];
  const float* Wc  = (const float*)d_in[16];
  const float* bc  = (const float*)d_in[17];

  char* w = (char*)d_ws;
  ushort_t* Qb  = (ushort_t*)w;                      w += (size_t)NROWS * QKD * 2;
  ushort_t* Kb  = (ushort_t*)w;                      w += (size_t)NROWS * QKD * 2;
  ushort_t* NVT = (ushort_t*)w;                      w += (size_t)NBATCH * QKD * NNODE * 2;
  float* pnv   = (float*)w;                          w += (size_t)NCHUNK * NROWS * NVD * 4;
  float* pm    = (float*)w;                          w += (size_t)NCHUNK * NROWS * 4;
  float* pl    = (float*)w;                          w += (size_t)NCHUNK * NROWS * 4;
  float* pse   = (float*)w;                          w += (size_t)NCHUNK * NROWS * 4;
  float* vals  = (float*)w;                          w += (size_t)NROWS * TRD * 4;
  float* stats = (float*)w;
  float* outp  = (float*)d_out;

  qkv_kernel<<<NROWS / 64, 256, 0, stream>>>(nodes, Wq, bq, Wk, bk, Wnv, bnv,
                                             Qb, Kb, NVT, stats);
  flashA_kernel<<<NBATCH * NCHUNK * (NNODE / RB), 256, 0, stream>>>(
      Qb, Kb, NVT, edges, dist, mask, pnv, pm, pl, pse);
  passBtrans_kernel<<<NROWS / 4, 256, 0, stream>>>(pnv, pm, pl, pse, Wev, bev,
                                                   Wt, bt, vals, stats);
  outbn_kernel<<<NROWS / 4, 256, 0, stream>>>(vals, stats, gamma, beta,
                                              Wc, bc, outp);
}

// Round 7
// 42.249 us; speedup vs baseline: 1.2384x; 1.2384x over previous
//
#include <hip/hip_runtime.h>
#include <math.h>

#define NNODE 512
#define NBATCH 4
#define NFEAT 12
#define QKD 128
#define NVD 128
#define EVD 32
#define CATD 160          // NVD + EVD
#define TRD 256
#define NCLS 5
#define NROWS 2048        // NBATCH * NNODE
#define EPSV 1e-5f
#define NSTATBUF 8        // split BN-stat atomic contention 8 ways
#define NCHUNK 4          // j-chunks per row (flash split)
#define JC 128            // j-chunk width
#define RB 16             // rows per flashA block (MFMA M=16)
#define SSW 132           // sS row stride (f32): +4 -> 2-way banks
#define KBW 136           // uKV row stride (ushort): 272B -> 2-way on frags

typedef float floatx4 __attribute__((ext_vector_type(4)));
typedef __bf16 bf16x8 __attribute__((ext_vector_type(8)));
typedef unsigned short ushort_t;
typedef ushort_t ushort8 __attribute__((ext_vector_type(8)));
typedef ushort_t ushort4v __attribute__((ext_vector_type(4)));

// f32 -> bf16 bits, round-to-nearest-even
static __device__ __forceinline__ ushort_t f2bf(float x) {
  unsigned int u = __float_as_uint(x);
  return (ushort_t)((u + 0x7fffu + ((u >> 16) & 1u)) >> 16);
}
static __device__ __forceinline__ bf16x8 pack8(ushort4v lo, ushort4v hi) {
  ushort8 u;
  u[0] = lo.x; u[1] = lo.y; u[2] = lo.z; u[3] = lo.w;
  u[4] = hi.x; u[5] = hi.y; u[6] = hi.z; u[7] = hi.w;
  return __builtin_bit_cast(bf16x8, u);
}

// ---------------------------------------------------------------------------
// Kernel 1: projections -> bf16 Qb[row][d], Kb[row][d], NVT[b][d][j].
// 128 blocks x 256 thr, 16 rows/block. Blocks 0..15 zero BN stats.
// ---------------------------------------------------------------------------
__global__ __launch_bounds__(256) void qkv_kernel(
    const float* __restrict__ nodes,
    const float* __restrict__ Wq, const float* __restrict__ bq,
    const float* __restrict__ Wk, const float* __restrict__ bk,
    const float* __restrict__ Wnv, const float* __restrict__ bnv,
    ushort_t* __restrict__ Qb, ushort_t* __restrict__ Kb,
    ushort_t* __restrict__ NVT, float* __restrict__ stats) {
  const int tid = threadIdx.x;
  const int blk = blockIdx.x;           // 0..127
  const int rowbase = blk * 16;
  const int b = rowbase >> 9;
  const int jloc = rowbase & (NNODE - 1);
  if (blk < 2 * NSTATBUF) stats[blk * 256 + tid] = 0.f;   // 16x256 = 4096
  __shared__ float sn[16][NFEAT];
  if (tid < 16 * NFEAT) ((float*)sn)[tid] = nodes[(size_t)rowbase * NFEAT + tid];
  __syncthreads();

  // ---- Q/K: thread owns d = tid&127; rows (tid>>7)*8 .. +7 --------------
  {
    const int d  = tid & 127;
    const int rg = tid >> 7;
    float wq[NFEAT], wk[NFEAT];
#pragma unroll
    for (int k = 0; k < NFEAT; ++k) {
      wq[k] = Wq[d * NFEAT + k];
      wk[k] = Wk[d * NFEAT + k];
    }
    const float bqv = bq[d], bkv = bk[d];
#pragma unroll
    for (int rr = 0; rr < 8; ++rr) {
      const int rl = rg * 8 + rr;
      float aq = bqv, ak = bkv;
#pragma unroll
      for (int k = 0; k < NFEAT; ++k) {
        const float n = sn[rl][k];
        aq = fmaf(n, wq[k], aq);
        ak = fmaf(n, wk[k], ak);
      }
      Qb[(size_t)(rowbase + rl) * QKD + d] = f2bf(aq);
      Kb[(size_t)(rowbase + rl) * QKD + d] = f2bf(ak);
    }
  }
  // ---- NV^T: thread owns d = tid>>1, half = tid&1 (8 j each) ------------
  {
    const int d    = tid >> 1;
    const int half = tid & 1;
    float wnv[NFEAT];
#pragma unroll
    for (int k = 0; k < NFEAT; ++k) wnv[k] = Wnv[d * NFEAT + k];
    const float bnvv = bnv[d];
    ushort8 v;
#pragma unroll
    for (int e = 0; e < 8; ++e) {
      const int rl = half * 8 + e;
      float av = bnvv;
#pragma unroll
      for (int k = 0; k < NFEAT; ++k) av = fmaf(sn[rl][k], wnv[k], av);
      v[e] = f2bf(av);
    }
    *(ushort8*)(NVT + (size_t)b * QKD * NNODE + (size_t)d * NNODE +
                jloc + half * 8) = v;
  }
}

// ---------------------------------------------------------------------------
// Kernel 2: flashA via MFMA. Block = (batch, chunk of 128 j, 16 rows).
// Grid 4*4*32 = 512, 256 thr (4 waves). Fragment layout (16x16x32 bf16):
//   A: lane l -> row=l&15, k = 4*(l>>4)+{0..3}, elems 4..7 at k+16
//   B: lane l -> col=l&15, same k pattern
//   C: lane l, reg r -> col=l&15, row=(l>>4)*4+r        [verified R5]
// ---------------------------------------------------------------------------
__global__ __launch_bounds__(256) void flashA_kernel(
    const ushort_t* __restrict__ Qb, const ushort_t* __restrict__ Kb,
    const ushort_t* __restrict__ NVT,
    const float* __restrict__ edges, const float* __restrict__ dist,
    const int* __restrict__ mask,
    float* __restrict__ pnv, float* __restrict__ pm,
    float* __restrict__ pl, float* __restrict__ pse) {
  __shared__ ushort_t uKV[QKD * KBW];   // union: sKB[128][136] / sNV[128][136]
  __shared__ __align__(16) float sS[RB][SSW];
  __shared__ float sM[RB], sL[RB], sSE[RB];

  const int tid = threadIdx.x;
  const int bid = blockIdx.x;           // 0..511
  const int b   = bid >> 7;             // batch
  const int c   = (bid >> 5) & 3;       // j-chunk
  const int rg  = bid & 31;             // row group
  const int rowbase = b * NNODE + rg * RB;
  const int jbase   = c * JC;

  const int lane = tid & 63;
  const int wv   = tid >> 6;            // wave 0..3
  const int col  = lane & 15;
  const int kg   = lane >> 4;

  // ---- prefetch dist/mask (2 j-tiles) + edges (softmax rows) ------------
  const int jl0 = (wv * 2) * 16 + col;
  const int jl1 = jl0 + 16;
  float d0a[4], d1a[4], ee0[4], ee1[4];
  int   m0a[4], m1a[4];
#pragma unroll
  for (int r = 0; r < 4; ++r) {
    const size_t off = (size_t)(rowbase + kg * 4 + r) * NNODE + jbase;
    d0a[r] = dist[off + jl0]; d1a[r] = dist[off + jl1];
    m0a[r] = mask[off + jl0]; m1a[r] = mask[off + jl1];
  }
#pragma unroll
  for (int rr = 0; rr < 4; ++rr) {
    const size_t base = (size_t)(rowbase + 4 * wv + rr) * NNODE + jbase;
    ee0[rr] = edges[base + lane];
    ee1[rr] = edges[base + 64 + lane];
  }

  // ---- stage K chunk -> sKB[128][136] (coalesced ushort8) ---------------
  ushort_t* sKB = uKV;
  {
    const int j  = tid >> 1;            // 0..127
    const int dh = (tid & 1) * 64;
    const ushort8* src =
        (const ushort8*)(Kb + (size_t)(b * NNODE + jbase + j) * QKD + dh);
    ushort8* dst = (ushort8*)(sKB + j * KBW + dh);
#pragma unroll
    for (int t = 0; t < 8; ++t) dst[t] = src[t];
  }
  // ---- Q A-fragments direct from global (bf16) --------------------------
  bf16x8 aq[4];
  {
    const ushort_t* Qr = Qb + (size_t)(rowbase + col) * QKD;
#pragma unroll
    for (int ks = 0; ks < 4; ++ks)
      aq[ks] = pack8(*(const ushort4v*)(Qr + ks * 32 + kg * 4),
                     *(const ushort4v*)(Qr + ks * 32 + 16 + kg * 4));
  }
  __syncthreads();

  // ---- QK^T: wave owns j-tiles {2wv, 2wv+1}; 8 MFMAs --------------------
  floatx4 acc0 = {0.f, 0.f, 0.f, 0.f};
  floatx4 acc1 = {0.f, 0.f, 0.f, 0.f};
  {
    const ushort_t* k0 = sKB + (size_t)(jl0) * KBW;
    const ushort_t* k1 = sKB + (size_t)(jl1) * KBW;
#pragma unroll
    for (int ks = 0; ks < 4; ++ks) {
      const bf16x8 b0 = pack8(*(const ushort4v*)(k0 + ks * 32 + kg * 4),
                              *(const ushort4v*)(k0 + ks * 32 + 16 + kg * 4));
      const bf16x8 b1 = pack8(*(const ushort4v*)(k1 + ks * 32 + kg * 4),
                              *(const ushort4v*)(k1 + ks * 32 + 16 + kg * 4));
      acc0 = __builtin_amdgcn_mfma_f32_16x16x32_bf16(aq[ks], b0, acc0, 0, 0, 0);
      acc1 = __builtin_amdgcn_mfma_f32_16x16x32_bf16(aq[ks], b1, acc1, 0, 0, 0);
    }
  }
  // ---- scores -> sS -----------------------------------------------------
  {
    const float coeff = 0.0883883476483184f;  // 1/sqrt(128)
#pragma unroll
    for (int r = 0; r < 4; ++r) {
      float s0 = acc0[r] * coeff / (d0a[r] + 1.0f);
      if (m0a[r]) s0 = -__builtin_inff();
      sS[kg * 4 + r][jl0] = s0;
      float s1 = acc1[r] * coeff / (d1a[r] + 1.0f);
      if (m1a[r]) s1 = -__builtin_inff();
      sS[kg * 4 + r][jl1] = s1;
    }
  }
  __syncthreads();                      // scores visible; sKB reads done

  // ---- issue NV staging loads early (hide under softmax) ----------------
  const int dnv = tid >> 1, half = tid & 1;
  ushort8 nvr[8];
  {
    const ushort8* nsrc = (const ushort8*)(NVT + (size_t)b * QKD * NNODE +
                                           (size_t)dnv * NNODE + jbase + half * 64);
#pragma unroll
    for (int t = 0; t < 8; ++t) nvr[t] = nsrc[t];
  }

  // ---- softmax partials (wave wv -> rows 4wv..4wv+3) --------------------
#pragma unroll
  for (int rr = 0; rr < 4; ++rr) {
    const int r = 4 * wv + rr;
    const float v0 = sS[r][lane];
    const float v1 = sS[r][lane + 64];
    float m = fmaxf(v0, v1);
#pragma unroll
    for (int s = 1; s < 64; s <<= 1) m = fmaxf(m, __shfl_xor(m, s, 64));
    float w0 = 0.f, w1 = 0.f;
    if (m > -__builtin_inff()) {        // wave-uniform
      w0 = __expf(v0 - m);
      w1 = __expf(v1 - m);
    }
    sS[r][lane]      = w0;
    sS[r][lane + 64] = w1;
    float l = w0 + w1;
    float se = fmaf(w0, ee0[rr], w1 * ee1[rr]);
#pragma unroll
    for (int s = 1; s < 64; s <<= 1) {
      l  += __shfl_xor(l, s, 64);
      se += __shfl_xor(se, s, 64);
    }
    if (lane == 0) { sM[r] = m; sL[r] = l; sSE[r] = se; }
  }
  // ---- write NV chunk into union buffer (sKB no longer needed) ----------
  ushort_t* sNV = uKV;
  {
    ushort8* nd = (ushort8*)(sNV + dnv * KBW + half * 64);
#pragma unroll
    for (int t = 0; t < 8; ++t) nd[t] = nvr[t];
  }
  __syncthreads();

  // ---- PV: pnv(16 x 128) = w(16 x 128j) @ NV(128j x 128d); 8 MFMAs ------
  bf16x8 aw[4];
#pragma unroll
  for (int ks = 0; ks < 4; ++ks) {
    const float4 lo = *(const float4*)&sS[col][ks * 32 + kg * 4];
    const float4 hi = *(const float4*)&sS[col][ks * 32 + 16 + kg * 4];
    ushort8 u;
    u[0] = f2bf(lo.x); u[1] = f2bf(lo.y); u[2] = f2bf(lo.z); u[3] = f2bf(lo.w);
    u[4] = f2bf(hi.x); u[5] = f2bf(hi.y); u[6] = f2bf(hi.z); u[7] = f2bf(hi.w);
    aw[ks] = __builtin_bit_cast(bf16x8, u);
  }
  floatx4 pv0 = {0.f, 0.f, 0.f, 0.f};
  floatx4 pv1 = {0.f, 0.f, 0.f, 0.f};
  {
    const ushort_t* n0 = sNV + (size_t)(wv * 32 + col) * KBW;
    const ushort_t* n1 = sNV + (size_t)(wv * 32 + 16 + col) * KBW;
#pragma unroll
    for (int ks = 0; ks < 4; ++ks) {
      const bf16x8 b0 = pack8(*(const ushort4v*)(n0 + ks * 32 + kg * 4),
                              *(const ushort4v*)(n0 + ks * 32 + 16 + kg * 4));
      const bf16x8 b1 = pack8(*(const ushort4v*)(n1 + ks * 32 + kg * 4),
                              *(const ushort4v*)(n1 + ks * 32 + 16 + kg * 4));
      pv0 = __builtin_amdgcn_mfma_f32_16x16x32_bf16(aw[ks], b0, pv0, 0, 0, 0);
      pv1 = __builtin_amdgcn_mfma_f32_16x16x32_bf16(aw[ks], b1, pv1, 0, 0, 0);
    }
  }
  // ---- write partials ---------------------------------------------------
#pragma unroll
  for (int r = 0; r < 4; ++r) {
    const size_t rowoff = ((size_t)c * NROWS + rowbase + kg * 4 + r) * NVD;
    pnv[rowoff + wv * 32 + col]      = pv0[r];
    pnv[rowoff + wv * 32 + 16 + col] = pv1[r];
  }
  if (tid < RB) {
    const int o = c * NROWS + rowbase + tid;
    pm[o] = sM[tid]; pl[o] = sL[tid]; pse[o] = sSE[tid];
  }
}

// ---------------------------------------------------------------------------
// Kernel 3: passB + transform fused. 512 blocks x 256 thr, 4 rows/block.
// ---------------------------------------------------------------------------
__global__ __launch_bounds__(256) void passBtrans_kernel(
    const float* __restrict__ pnv, const float* __restrict__ pm,
    const float* __restrict__ pl, const float* __restrict__ pse,
    const float* __restrict__ Wev, const float* __restrict__ bev,
    const float* __restrict__ Wt, const float* __restrict__ bt,
    float* __restrict__ vals, float* __restrict__ stats) {
  __shared__ __align__(16) float sC[4][CATD];     // 2.5 KB
  const int tid = threadIdx.x;
  const int bid = blockIdx.x;          // 0..511
  const int row0 = bid * 4;

#pragma unroll
  for (int k = 0; k < 2; ++k) {
    const int idx = tid + k * 256;
    const int r = idx >> 7, d = idx & 127;
    const int row = row0 + r;
    float mg = -__builtin_inff();
#pragma unroll
    for (int c = 0; c < NCHUNK; ++c) mg = fmaxf(mg, pm[c * NROWS + row]);
    float lg = 0.f, nv = 0.f;
#pragma unroll
    for (int c = 0; c < NCHUNK; ++c) {
      const float mc = pm[c * NROWS + row];
      if (mc > -__builtin_inff()) {
        const float sc = __expf(mc - mg);
        lg = fmaf(pl[c * NROWS + row], sc, lg);
        nv = fmaf(pnv[((size_t)c * NROWS + row) * NVD + d], sc, nv);
      }
    }
    const float inv = (lg > 0.f) ? 1.f / lg : 0.f;
    sC[r][d] = tanhf(nv * inv);
  }
  if (tid < 4 * EVD) {
    const int r = tid >> 5, de = tid & 31;
    const int row = row0 + r;
    float mg = -__builtin_inff();
#pragma unroll
    for (int c = 0; c < NCHUNK; ++c) mg = fmaxf(mg, pm[c * NROWS + row]);
    float lg = 0.f, seg = 0.f;
#pragma unroll
    for (int c = 0; c < NCHUNK; ++c) {
      const float mc = pm[c * NROWS + row];
      if (mc > -__builtin_inff()) {
        const float sc = __expf(mc - mg);
        lg  = fmaf(pl[c * NROWS + row], sc, lg);
        seg = fmaf(pse[c * NROWS + row], sc, seg);
      }
    }
    const float sw = (lg > 0.f) ? 1.f : 0.f;
    const float se = (lg > 0.f) ? seg / lg : 0.f;
    sC[r][NVD + de] = tanhf(fmaf(Wev[de], se, bev[de] * sw));
  }
  __syncthreads();

  const int o = tid;
  const float4* __restrict__ w4 = (const float4*)(Wt + (size_t)o * CATD);
  float acc[4] = {0.f, 0.f, 0.f, 0.f};
#pragma unroll 8
  for (int k4 = 0; k4 < CATD / 4; ++k4) {
    const float4 w = w4[k4];
#pragma unroll
    for (int r = 0; r < 4; ++r) {
      const float4 cc = ((const float4*)sC[r])[k4];
      acc[r] += cc.x * w.x + cc.y * w.y + cc.z * w.z + cc.w * w.w;
    }
  }
  const float bto = bt[o];
  float s1 = 0.f, s2 = 0.f;
#pragma unroll
  for (int r = 0; r < 4; ++r) {
    const float v2 = acc[r] + bto;
    vals[(size_t)(row0 + r) * TRD + o] = v2;
    s1 += v2;
    s2 = fmaf(v2, v2, s2);
  }
  float* sb = stats + (size_t)(bid & (NSTATBUF - 1)) * 2 * TRD;
  atomicAdd(&sb[o], s1);
  atomicAdd(&sb[TRD + o], s2);
}

// ---------------------------------------------------------------------------
// Kernel 4: fused BN-fold + classifier. 512 blocks x 256 thr, 4 rows/block.
// ---------------------------------------------------------------------------
__global__ __launch_bounds__(256) void outbn_kernel(
    const float* __restrict__ vals, const float* __restrict__ stats,
    const float* __restrict__ gamma, const float* __restrict__ beta,
    const float* __restrict__ Wc, const float* __restrict__ bc,
    float* __restrict__ out) {
  __shared__ float sW[NCLS][TRD];
  __shared__ float sb[NCLS];
  __shared__ float red[4][NCLS];
  const int tid = threadIdx.x;
  const int o = tid;                   // 0..255
  float s1 = 0.f, s2 = 0.f;
#pragma unroll
  for (int k = 0; k < NSTATBUF; ++k) {
    s1 += stats[k * 2 * TRD + o];
    s2 += stats[k * 2 * TRD + TRD + o];
  }
  const float invN = 1.0f / (float)NROWS;
  const float mu  = s1 * invN;
  const float var = s2 * invN - mu * mu;
  const float inv = 1.0f / sqrtf(var + EPSV);
  const float g = gamma[o] * inv;
  const float bterm = beta[o] - mu * g;
  float v[NCLS];
#pragma unroll
  for (int c = 0; c < NCLS; ++c) {
    const float wc = Wc[c * TRD + o];
    sW[c][o] = wc * g;
    v[c] = wc * bterm;
  }
#pragma unroll
  for (int s = 1; s < 64; s <<= 1) {
#pragma unroll
    for (int c = 0; c < NCLS; ++c) v[c] += __shfl_xor(v[c], s, 64);
  }
  if ((tid & 63) == 0) {
#pragma unroll
    for (int c = 0; c < NCLS; ++c) red[tid >> 6][c] = v[c];
  }
  __syncthreads();
  if (tid < NCLS)
    sb[tid] = bc[tid] + red[0][tid] + red[1][tid] + red[2][tid] + red[3][tid];
  __syncthreads();

  const int lane = tid & 63;
  const int row = blockIdx.x * 4 + (tid >> 6);
  float vv[TRD / 64];
#pragma unroll
  for (int t = 0; t < TRD / 64; ++t)
    vv[t] = vals[(size_t)row * TRD + lane + 64 * t];
#pragma unroll
  for (int c = 0; c < NCLS; ++c) {
    float p = 0.f;
#pragma unroll
    for (int t = 0; t < TRD / 64; ++t)
      p = fmaf(vv[t], sW[c][lane + 64 * t], p);
#pragma unroll
    for (int s = 1; s < 64; s <<= 1) p += __shfl_xor(p, s, 64);
    if (lane == 0) out[(size_t)row * NCLS + c] = p + sb[c];
  }
}

// ---------------------------------------------------------------------------
extern "C" void kernel_launch(void* const* d_in, const int* in_sizes, int n_in,
                              void* d_out, int out_size, void* d_ws, size_t ws_size,
                              hipStream_t stream) {
  (void)in_sizes; (void)n_in; (void)out_size; (void)ws_size;
  const float* nodes = (const float*)d_in[0];
  const float* edges = (const float*)d_in[1];
  const float* dist  = (const float*)d_in[2];
  const int*   mask  = (const int*)d_in[3];
  const float* Wq  = (const float*)d_in[4];
  const float* bq  = (const float*)d_in[5];
  const float* Wk  = (const float*)d_in[6];
  const float* bk  = (const float*)d_in[7];
  const float* Wnv = (const float*)d_in[8];
  const float* bnv = (const float*)d_in[9];
  const float* Wev = (const float*)d_in[10];
  const float* bev = (const float*)d_in[11];
  const float* Wt  = (const float*)d_in[12];
  const float* bt  = (const float*)d_in[13];
  const float* gamma = (const float*)d_in[14];
  const float* beta  = (const float*)d_in[15];
  const float* Wc  = (const float*)d_in[16];
  const float* bc  = (const float*)d_in[17];

  char* w = (char*)d_ws;
  ushort_t* Qb  = (ushort_t*)w;                      w += (size_t)NROWS * QKD * 2;
  ushort_t* Kb  = (ushort_t*)w;                      w += (size_t)NROWS * QKD * 2;
  ushort_t* NVT = (ushort_t*)w;                      w += (size_t)NBATCH * QKD * NNODE * 2;
  float* pnv   = (float*)w;                          w += (size_t)NCHUNK * NROWS * NVD * 4;
  float* pm    = (float*)w;                          w += (size_t)NCHUNK * NROWS * 4;
  float* pl    = (float*)w;                          w += (size_t)NCHUNK * NROWS * 4;
  float* pse   = (float*)w;                          w += (size_t)NCHUNK * NROWS * 4;
  float* vals  = (float*)w;                          w += (size_t)NROWS * TRD * 4;
  float* stats = (float*)w;
  float* outp  = (float*)d_out;

  qkv_kernel<<<NROWS / 16, 256, 0, stream>>>(nodes, Wq, bq, Wk, bk, Wnv, bnv,
                                             Qb, Kb, NVT, stats);
  flashA_kernel<<<NBATCH * NCHUNK * (NNODE / RB), 256, 0, stream>>>(
      Qb, Kb, NVT, edges, dist, mask, pnv, pm, pl, pse);
  passBtrans_kernel<<<NROWS / 4, 256, 0, stream>>>(pnv, pm, pl, pse, Wev, bev,
                                                   Wt, bt, vals, stats);
  outbn_kernel<<<NROWS / 4, 256, 0, stream>>>(vals, stats, gamma, beta,
                                              Wc, bc, outp);
}

// Round 8
// 34.556 us; speedup vs baseline: 1.5141x; 1.2226x over previous
//
#include <hip/hip_runtime.h>
#include <math.h>

#define NNODE 512
#define NBATCH 4
#define NFEAT 12
#define QKD 128
#define NVD 128
#define EVD 32
#define CATD 160          // NVD + EVD
#define CATB 168          // catb LDS stride (bf16)
#define TRD 256
#define NCLS 5
#define NROWS 2048        // NBATCH * NNODE
#define EPSV 1e-5f
#define NSTATBUF 8        // split BN-stat atomic contention 8 ways
#define NCHUNK 4          // j-chunks per row (flash split)
#define JC 128            // j-chunk width
#define RB 16             // rows per flashA / passB block (MFMA M=16)
#define SSW 132           // sS row stride (f32): +4 -> 2-way banks
#define KBW 136           // K/NV LDS row stride (ushort): 272B -> ~2-way

typedef float floatx4 __attribute__((ext_vector_type(4)));
typedef __bf16 bf16x8 __attribute__((ext_vector_type(8)));
typedef unsigned short ushort_t;
typedef ushort_t ushort8 __attribute__((ext_vector_type(8)));
typedef ushort_t ushort4v __attribute__((ext_vector_type(4)));

// f32 -> bf16 bits, round-to-nearest-even
static __device__ __forceinline__ ushort_t f2bf(float x) {
  unsigned int u = __float_as_uint(x);
  return (ushort_t)((u + 0x7fffu + ((u >> 16) & 1u)) >> 16);
}
static __device__ __forceinline__ bf16x8 pack8(ushort4v lo, ushort4v hi) {
  ushort8 u;
  u[0] = lo.x; u[1] = lo.y; u[2] = lo.z; u[3] = lo.w;
  u[4] = hi.x; u[5] = hi.y; u[6] = hi.z; u[7] = hi.w;
  return __builtin_bit_cast(bf16x8, u);
}

// ---------------------------------------------------------------------------
// Kernel 1: projections -> bf16 Qb[row][d], Kb[row][d], NVT[b][d][j],
// Wtb[o][k] (bf16 copy of Wt). 128 blocks x 256 thr, 16 rows/block.
// Blocks 0..15 zero BN stats.
// ---------------------------------------------------------------------------
__global__ __launch_bounds__(256) void qkv_kernel(
    const float* __restrict__ nodes,
    const float* __restrict__ Wq, const float* __restrict__ bq,
    const float* __restrict__ Wk, const float* __restrict__ bk,
    const float* __restrict__ Wnv, const float* __restrict__ bnv,
    const float* __restrict__ Wt,
    ushort_t* __restrict__ Qb, ushort_t* __restrict__ Kb,
    ushort_t* __restrict__ NVT, ushort_t* __restrict__ Wtb,
    float* __restrict__ stats) {
  const int tid = threadIdx.x;
  const int blk = blockIdx.x;           // 0..127
  const int rowbase = blk * 16;
  const int b = rowbase >> 9;
  const int jloc = rowbase & (NNODE - 1);
  if (blk < 2 * NSTATBUF) stats[blk * 256 + tid] = 0.f;   // 16x256 = 4096
  {  // Wt -> bf16: 40960 elems, 320 per block
    const int base = blk * 320;
    Wtb[base + tid] = f2bf(Wt[base + tid]);
    if (tid < 64) Wtb[base + 256 + tid] = f2bf(Wt[base + 256 + tid]);
  }
  __shared__ float sn[16][NFEAT];
  if (tid < 16 * NFEAT) ((float*)sn)[tid] = nodes[(size_t)rowbase * NFEAT + tid];
  __syncthreads();

  // ---- Q/K: thread owns d = tid&127; rows (tid>>7)*8 .. +7 --------------
  {
    const int d  = tid & 127;
    const int rg = tid >> 7;
    float wq[NFEAT], wk[NFEAT];
#pragma unroll
    for (int k = 0; k < NFEAT; ++k) {
      wq[k] = Wq[d * NFEAT + k];
      wk[k] = Wk[d * NFEAT + k];
    }
    const float bqv = bq[d], bkv = bk[d];
#pragma unroll
    for (int rr = 0; rr < 8; ++rr) {
      const int rl = rg * 8 + rr;
      float aq = bqv, ak = bkv;
#pragma unroll
      for (int k = 0; k < NFEAT; ++k) {
        const float n = sn[rl][k];
        aq = fmaf(n, wq[k], aq);
        ak = fmaf(n, wk[k], ak);
      }
      Qb[(size_t)(rowbase + rl) * QKD + d] = f2bf(aq);
      Kb[(size_t)(rowbase + rl) * QKD + d] = f2bf(ak);
    }
  }
  // ---- NV^T: thread owns d = tid>>1, half = tid&1 (8 j each) ------------
  {
    const int d    = tid >> 1;
    const int half = tid & 1;
    float wnv[NFEAT];
#pragma unroll
    for (int k = 0; k < NFEAT; ++k) wnv[k] = Wnv[d * NFEAT + k];
    const float bnvv = bnv[d];
    ushort8 v;
#pragma unroll
    for (int e = 0; e < 8; ++e) {
      const int rl = half * 8 + e;
      float av = bnvv;
#pragma unroll
      for (int k = 0; k < NFEAT; ++k) av = fmaf(sn[rl][k], wnv[k], av);
      v[e] = f2bf(av);
    }
    *(ushort8*)(NVT + (size_t)b * QKD * NNODE + (size_t)d * NNODE +
                jloc + half * 8) = v;
  }
}

// ---------------------------------------------------------------------------
// Kernel 2: flashA via MFMA. Block = (batch, chunk of 128 j, 16 rows).
// Grid 512, 256 thr (4 waves). K and NV both staged up-front (separate LDS).
//   A: lane l -> row=l&15, k = 4*(l>>4)+{0..3}, elems 4..7 at k+16
//   B: lane l -> col=l&15, same k pattern
//   C: lane l, reg r -> col=l&15, row=(l>>4)*4+r        [verified R5]
// ---------------------------------------------------------------------------
__global__ __launch_bounds__(256) void flashA_kernel(
    const ushort_t* __restrict__ Qb, const ushort_t* __restrict__ Kb,
    const ushort_t* __restrict__ NVT,
    const float* __restrict__ edges, const float* __restrict__ dist,
    const int* __restrict__ mask,
    float* __restrict__ pnv, float* __restrict__ pm,
    float* __restrict__ pl, float* __restrict__ pse) {
  __shared__ ushort_t sKB[JC * KBW];    // 34.8 KB
  __shared__ ushort_t sNV[QKD * KBW];   // 34.8 KB
  __shared__ __align__(16) float sS[RB][SSW];   // 8.4 KB
  __shared__ float sM[RB], sL[RB], sSEr[RB];

  const int tid = threadIdx.x;
  const int bid = blockIdx.x;           // 0..511
  const int b   = bid >> 7;             // batch
  const int c   = (bid >> 5) & 3;       // j-chunk
  const int rg  = bid & 31;             // row group
  const int rowbase = b * NNODE + rg * RB;
  const int jbase   = c * JC;

  const int lane = tid & 63;
  const int wv   = tid >> 6;            // wave 0..3
  const int col  = lane & 15;
  const int kg   = lane >> 4;

  // ---- prefetch dist/mask (2 j-tiles) + edges (softmax rows) ------------
  const int jl0 = (wv * 2) * 16 + col;
  const int jl1 = jl0 + 16;
  float d0a[4], d1a[4], ee0[4], ee1[4];
  int   m0a[4], m1a[4];
#pragma unroll
  for (int r = 0; r < 4; ++r) {
    const size_t off = (size_t)(rowbase + kg * 4 + r) * NNODE + jbase;
    d0a[r] = dist[off + jl0]; d1a[r] = dist[off + jl1];
    m0a[r] = mask[off + jl0]; m1a[r] = mask[off + jl1];
  }
#pragma unroll
  for (int rr = 0; rr < 4; ++rr) {
    const size_t base = (size_t)(rowbase + 4 * wv + rr) * NNODE + jbase;
    ee0[rr] = edges[base + lane];
    ee1[rr] = edges[base + 64 + lane];
  }

  // ---- stage K chunk AND NV chunk up-front (both coalesced ushort8) -----
  {
    const int j  = tid >> 1;            // 0..127
    const int dh = (tid & 1) * 64;
    const ushort8* ksrc =
        (const ushort8*)(Kb + (size_t)(b * NNODE + jbase + j) * QKD + dh);
    ushort8* kdst = (ushort8*)(sKB + j * KBW + dh);
#pragma unroll
    for (int t = 0; t < 8; ++t) kdst[t] = ksrc[t];
    const ushort8* nsrc = (const ushort8*)(NVT + (size_t)b * QKD * NNODE +
                                           (size_t)j * NNODE + jbase + dh);
    ushort8* ndst = (ushort8*)(sNV + j * KBW + dh);
#pragma unroll
    for (int t = 0; t < 8; ++t) ndst[t] = nsrc[t];
  }
  // ---- Q A-fragments direct from global (bf16) --------------------------
  bf16x8 aq[4];
  {
    const ushort_t* Qr = Qb + (size_t)(rowbase + col) * QKD;
#pragma unroll
    for (int ks = 0; ks < 4; ++ks)
      aq[ks] = pack8(*(const ushort4v*)(Qr + ks * 32 + kg * 4),
                     *(const ushort4v*)(Qr + ks * 32 + 16 + kg * 4));
  }
  __syncthreads();

  // ---- QK^T: wave owns j-tiles {2wv, 2wv+1}; 8 MFMAs --------------------
  floatx4 acc0 = {0.f, 0.f, 0.f, 0.f};
  floatx4 acc1 = {0.f, 0.f, 0.f, 0.f};
  {
    const ushort_t* k0 = sKB + (size_t)jl0 * KBW;
    const ushort_t* k1 = sKB + (size_t)jl1 * KBW;
#pragma unroll
    for (int ks = 0; ks < 4; ++ks) {
      const bf16x8 b0 = pack8(*(const ushort4v*)(k0 + ks * 32 + kg * 4),
                              *(const ushort4v*)(k0 + ks * 32 + 16 + kg * 4));
      const bf16x8 b1 = pack8(*(const ushort4v*)(k1 + ks * 32 + kg * 4),
                              *(const ushort4v*)(k1 + ks * 32 + 16 + kg * 4));
      acc0 = __builtin_amdgcn_mfma_f32_16x16x32_bf16(aq[ks], b0, acc0, 0, 0, 0);
      acc1 = __builtin_amdgcn_mfma_f32_16x16x32_bf16(aq[ks], b1, acc1, 0, 0, 0);
    }
  }
  // ---- scores -> sS -----------------------------------------------------
  {
    const float coeff = 0.0883883476483184f;  // 1/sqrt(128)
#pragma unroll
    for (int r = 0; r < 4; ++r) {
      float s0 = acc0[r] * coeff / (d0a[r] + 1.0f);
      if (m0a[r]) s0 = -__builtin_inff();
      sS[kg * 4 + r][jl0] = s0;
      float s1 = acc1[r] * coeff / (d1a[r] + 1.0f);
      if (m1a[r]) s1 = -__builtin_inff();
      sS[kg * 4 + r][jl1] = s1;
    }
  }
  __syncthreads();

  // ---- softmax partials (wave wv -> rows 4wv..4wv+3) --------------------
#pragma unroll
  for (int rr = 0; rr < 4; ++rr) {
    const int r = 4 * wv + rr;
    const float v0 = sS[r][lane];
    const float v1 = sS[r][lane + 64];
    float m = fmaxf(v0, v1);
#pragma unroll
    for (int s = 1; s < 64; s <<= 1) m = fmaxf(m, __shfl_xor(m, s, 64));
    float w0 = 0.f, w1 = 0.f;
    if (m > -__builtin_inff()) {        // wave-uniform
      w0 = __expf(v0 - m);
      w1 = __expf(v1 - m);
    }
    sS[r][lane]      = w0;
    sS[r][lane + 64] = w1;
    float l = w0 + w1;
    float se = fmaf(w0, ee0[rr], w1 * ee1[rr]);
#pragma unroll
    for (int s = 1; s < 64; s <<= 1) {
      l  += __shfl_xor(l, s, 64);
      se += __shfl_xor(se, s, 64);
    }
    if (lane == 0) { sM[r] = m; sL[r] = l; sSEr[r] = se; }
  }
  __syncthreads();

  // ---- PV: pnv(16 x 128) = w(16 x 128j) @ NV(128j x 128d); 8 MFMAs ------
  bf16x8 aw[4];
#pragma unroll
  for (int ks = 0; ks < 4; ++ks) {
    const float4 lo = *(const float4*)&sS[col][ks * 32 + kg * 4];
    const float4 hi = *(const float4*)&sS[col][ks * 32 + 16 + kg * 4];
    ushort8 u;
    u[0] = f2bf(lo.x); u[1] = f2bf(lo.y); u[2] = f2bf(lo.z); u[3] = f2bf(lo.w);
    u[4] = f2bf(hi.x); u[5] = f2bf(hi.y); u[6] = f2bf(hi.z); u[7] = f2bf(hi.w);
    aw[ks] = __builtin_bit_cast(bf16x8, u);
  }
  floatx4 pv0 = {0.f, 0.f, 0.f, 0.f};
  floatx4 pv1 = {0.f, 0.f, 0.f, 0.f};
  {
    const ushort_t* n0 = sNV + (size_t)(wv * 32 + col) * KBW;
    const ushort_t* n1 = sNV + (size_t)(wv * 32 + 16 + col) * KBW;
#pragma unroll
    for (int ks = 0; ks < 4; ++ks) {
      const bf16x8 b0 = pack8(*(const ushort4v*)(n0 + ks * 32 + kg * 4),
                              *(const ushort4v*)(n0 + ks * 32 + 16 + kg * 4));
      const bf16x8 b1 = pack8(*(const ushort4v*)(n1 + ks * 32 + kg * 4),
                              *(const ushort4v*)(n1 + ks * 32 + 16 + kg * 4));
      pv0 = __builtin_amdgcn_mfma_f32_16x16x32_bf16(aw[ks], b0, pv0, 0, 0, 0);
      pv1 = __builtin_amdgcn_mfma_f32_16x16x32_bf16(aw[ks], b1, pv1, 0, 0, 0);
    }
  }
  // ---- write partials ---------------------------------------------------
#pragma unroll
  for (int r = 0; r < 4; ++r) {
    const size_t rowoff = ((size_t)c * NROWS + rowbase + kg * 4 + r) * NVD;
    pnv[rowoff + wv * 32 + col]      = pv0[r];
    pnv[rowoff + wv * 32 + 16 + col] = pv1[r];
  }
  if (tid < RB) {
    const int o = c * NROWS + rowbase + tid;
    pm[o] = sM[tid]; pl[o] = sL[tid]; pse[o] = sSEr[tid];
  }
}

// ---------------------------------------------------------------------------
// Kernel 3: passB + transform via MFMA. 128 blocks x 256 thr, 16 rows/block.
//   step1 (threads 0..15): per-row chunk factors fac[c], se, sw
//   step2: catb[16][CATD] = tanh(combined) in bf16 LDS
//   step3: vals = catb @ Wtb^T + bt  (MFMA, B-frags from global Wtb)
//          + BN stat atomics (shuffle-reduced, 16 lanes/wave)
// ---------------------------------------------------------------------------
__global__ __launch_bounds__(256) void passBtrans_kernel(
    const float* __restrict__ pnv, const float* __restrict__ pm,
    const float* __restrict__ pl, const float* __restrict__ pse,
    const float* __restrict__ Wev, const float* __restrict__ bev,
    const ushort_t* __restrict__ Wtb, const float* __restrict__ bt,
    float* __restrict__ vals, float* __restrict__ stats) {
  __shared__ ushort_t catb[RB * CATB];  // 5.25 KB
  __shared__ float sFac[NCHUNK][RB], sSe[RB], sSw[RB];
  const int tid = threadIdx.x;
  const int bid = blockIdx.x;           // 0..127
  const int row0 = bid * RB;

  // ---- step1: per-row combine factors -----------------------------------
  if (tid < RB) {
    const int row = row0 + tid;
    float mv[NCHUNK];
    float mg = -__builtin_inff();
#pragma unroll
    for (int c = 0; c < NCHUNK; ++c) {
      mv[c] = pm[c * NROWS + row];
      mg = fmaxf(mg, mv[c]);
    }
    float lg = 0.f, seg = 0.f, fa[NCHUNK];
#pragma unroll
    for (int c = 0; c < NCHUNK; ++c) {
      const float s = (mv[c] > -__builtin_inff()) ? __expf(mv[c] - mg) : 0.f;
      fa[c] = s;
      lg  = fmaf(pl[c * NROWS + row], s, lg);
      seg = fmaf(pse[c * NROWS + row], s, seg);
    }
    const float inv = (lg > 0.f) ? 1.f / lg : 0.f;
#pragma unroll
    for (int c = 0; c < NCHUNK; ++c) sFac[c][tid] = fa[c] * inv;
    sSe[tid] = seg * inv;
    sSw[tid] = (lg > 0.f) ? 1.f : 0.f;
  }
  __syncthreads();

  // ---- step2: catb = tanh(node | edge) ----------------------------------
#pragma unroll
  for (int k = 0; k < 8; ++k) {         // 16x128 node elems, 8/thread
    const int idx = tid + k * 256;
    const int r = idx >> 7, d = idx & 127;
    float nv = 0.f;
#pragma unroll
    for (int c = 0; c < NCHUNK; ++c)
      nv = fmaf(pnv[((size_t)c * NROWS + row0 + r) * NVD + d], sFac[c][r], nv);
    catb[r * CATB + d] = f2bf(tanhf(nv));
  }
#pragma unroll
  for (int k = 0; k < 2; ++k) {         // 16x32 edge elems, 2/thread
    const int idx = tid + k * 256;
    const int r = idx >> 5, de = idx & 31;
    catb[r * CATB + NVD + de] =
        f2bf(tanhf(fmaf(Wev[de], sSe[r], bev[de] * sSw[r])));
  }
  __syncthreads();

  // ---- step3: MFMA transform -------------------------------------------
  const int lane = tid & 63;
  const int wv   = tid >> 6;
  const int col  = lane & 15;
  const int kg   = lane >> 4;
  bf16x8 af[5];                         // A-frags: K=160 -> 5 frags
#pragma unroll
  for (int ks = 0; ks < 5; ++ks) {
    const ushort_t* cr = catb + col * CATB + ks * 32;
    af[ks] = pack8(*(const ushort4v*)(cr + kg * 4),
                   *(const ushort4v*)(cr + 16 + kg * 4));
  }
  float* sbuf = stats + (size_t)(bid & (NSTATBUF - 1)) * 2 * TRD;
#pragma unroll
  for (int t = 0; t < 4; ++t) {         // 4 col-tiles per wave
    const int o = (wv * 4 + t) * 16 + col;
    const ushort_t* wr = Wtb + (size_t)o * CATD;
    floatx4 acc = {0.f, 0.f, 0.f, 0.f};
#pragma unroll
    for (int ks = 0; ks < 5; ++ks) {
      const bf16x8 bf = pack8(*(const ushort4v*)(wr + ks * 32 + kg * 4),
                              *(const ushort4v*)(wr + ks * 32 + 16 + kg * 4));
      acc = __builtin_amdgcn_mfma_f32_16x16x32_bf16(af[ks], bf, acc, 0, 0, 0);
    }
    const float bto = bt[o];
    float s1 = 0.f, s2 = 0.f;
#pragma unroll
    for (int r = 0; r < 4; ++r) {
      const float v2 = acc[r] + bto;
      vals[(size_t)(row0 + kg * 4 + r) * TRD + o] = v2;
      s1 += v2;
      s2 = fmaf(v2, v2, s2);
    }
    s1 += __shfl_xor(s1, 16, 64); s2 += __shfl_xor(s2, 16, 64);
    s1 += __shfl_xor(s1, 32, 64); s2 += __shfl_xor(s2, 32, 64);
    if (kg == 0) {
      atomicAdd(&sbuf[o], s1);
      atomicAdd(&sbuf[TRD + o], s2);
    }
  }
}

// ---------------------------------------------------------------------------
// Kernel 4: fused BN-fold + classifier. 512 blocks x 256 thr, 4 rows/block.
// ---------------------------------------------------------------------------
__global__ __launch_bounds__(256) void outbn_kernel(
    const float* __restrict__ vals, const float* __restrict__ stats,
    const float* __restrict__ gamma, const float* __restrict__ beta,
    const float* __restrict__ Wc, const float* __restrict__ bc,
    float* __restrict__ out) {
  __shared__ float sW[NCLS][TRD];
  __shared__ float sb[NCLS];
  __shared__ float red[4][NCLS];
  const int tid = threadIdx.x;
  const int o = tid;                   // 0..255
  float s1 = 0.f, s2 = 0.f;
#pragma unroll
  for (int k = 0; k < NSTATBUF; ++k) {
    s1 += stats[k * 2 * TRD + o];
    s2 += stats[k * 2 * TRD + TRD + o];
  }
  const float invN = 1.0f / (float)NROWS;
  const float mu  = s1 * invN;
  const float var = s2 * invN - mu * mu;
  const float inv = 1.0f / sqrtf(var + EPSV);
  const float g = gamma[o] * inv;
  const float bterm = beta[o] - mu * g;
  float v[NCLS];
#pragma unroll
  for (int c = 0; c < NCLS; ++c) {
    const float wc = Wc[c * TRD + o];
    sW[c][o] = wc * g;
    v[c] = wc * bterm;
  }
#pragma unroll
  for (int s = 1; s < 64; s <<= 1) {
#pragma unroll
    for (int c = 0; c < NCLS; ++c) v[c] += __shfl_xor(v[c], s, 64);
  }
  if ((tid & 63) == 0) {
#pragma unroll
    for (int c = 0; c < NCLS; ++c) red[tid >> 6][c] = v[c];
  }
  __syncthreads();
  if (tid < NCLS)
    sb[tid] = bc[tid] + red[0][tid] + red[1][tid] + red[2][tid] + red[3][tid];
  __syncthreads();

  const int lane = tid & 63;
  const int row = blockIdx.x * 4 + (tid >> 6);
  float vv[TRD / 64];
#pragma unroll
  for (int t = 0; t < TRD / 64; ++t)
    vv[t] = vals[(size_t)row * TRD + lane + 64 * t];
#pragma unroll
  for (int c = 0; c < NCLS; ++c) {
    float p = 0.f;
#pragma unroll
    for (int t = 0; t < TRD / 64; ++t)
      p = fmaf(vv[t], sW[c][lane + 64 * t], p);
#pragma unroll
    for (int s = 1; s < 64; s <<= 1) p += __shfl_xor(p, s, 64);
    if (lane == 0) out[(size_t)row * NCLS + c] = p + sb[c];
  }
}

// ---------------------------------------------------------------------------
extern "C" void kernel_launch(void* const* d_in, const int* in_sizes, int n_in,
                              void* d_out, int out_size, void* d_ws, size_t ws_size,
                              hipStream_t stream) {
  (void)in_sizes; (void)n_in; (void)out_size; (void)ws_size;
  const float* nodes = (const float*)d_in[0];
  const float* edges = (const float*)d_in[1];
  const float* dist  = (const float*)d_in[2];
  const int*   mask  = (const int*)d_in[3];
  const float* Wq  = (const float*)d_in[4];
  const float* bq  = (const float*)d_in[5];
  const float* Wk  = (const float*)d_in[6];
  const float* bk  = (const float*)d_in[7];
  const float* Wnv = (const float*)d_in[8];
  const float* bnv = (const float*)d_in[9];
  const float* Wev = (const float*)d_in[10];
  const float* bev = (const float*)d_in[11];
  const float* Wt  = (const float*)d_in[12];
  const float* bt  = (const float*)d_in[13];
  const float* gamma = (const float*)d_in[14];
  const float* beta  = (const float*)d_in[15];
  const float* Wc  = (const float*)d_in[16];
  const float* bc  = (const float*)d_in[17];

  char* w = (char*)d_ws;
  ushort_t* Qb  = (ushort_t*)w;                      w += (size_t)NROWS * QKD * 2;
  ushort_t* Kb  = (ushort_t*)w;                      w += (size_t)NROWS * QKD * 2;
  ushort_t* NVT = (ushort_t*)w;                      w += (size_t)NBATCH * QKD * NNODE * 2;
  ushort_t* Wtb = (ushort_t*)w;                      w += (size_t)TRD * CATD * 2;
  float* pnv   = (float*)w;                          w += (size_t)NCHUNK * NROWS * NVD * 4;
  float* pm    = (float*)w;                          w += (size_t)NCHUNK * NROWS * 4;
  float* pl    = (float*)w;                          w += (size_t)NCHUNK * NROWS * 4;
  float* pse   = (float*)w;                          w += (size_t)NCHUNK * NROWS * 4;
  float* vals  = (float*)w;                          w += (size_t)NROWS * TRD * 4;
  float* stats = (float*)w;
  float* outp  = (float*)d_out;

  qkv_kernel<<<NROWS / 16, 256, 0, stream>>>(nodes, Wq, bq, Wk, bk, Wnv, bnv,
                                             Wt, Qb, Kb, NVT, Wtb, stats);
  flashA_kernel<<<NBATCH * NCHUNK * (NNODE / RB), 256, 0, stream>>>(
      Qb, Kb, NVT, edges, dist, mask, pnv, pm, pl, pse);
  passBtrans_kernel<<<NROWS / 16, 256, 0, stream>>>(pnv, pm, pl, pse, Wev, bev,
                                                    Wtb, bt, vals, stats);
  outbn_kernel<<<NROWS / 4, 256, 0, stream>>>(vals, stats, gamma, beta,
                                              Wc, bc, outp);
}

// Round 9
// 34.171 us; speedup vs baseline: 1.5311x; 1.0113x over previous
//
#include <hip/hip_runtime.h>
#include <math.h>

#define NNODE 512
#define NBATCH 4
#define NFEAT 12
#define QKD 128
#define NVD 128
#define EVD 32
#define CATD 160          // NVD + EVD
#define CATB 168          // catb LDS stride (bf16)
#define TRD 256
#define NCLS 5
#define NROWS 2048        // NBATCH * NNODE
#define EPSV 1e-5f
#define NSTATBUF 8        // split BN-stat atomic contention 8 ways
#define NCHUNK 4          // j-chunks (online-softmax loop)
#define JC 128            // j-chunk width
#define RPB 8             // query rows per attnTrans block
#define SSW 132           // sS row stride (f32), 16B-aligned rows
#define KBW 136           // K/NV LDS row stride (ushort), 16B-aligned rows

typedef float floatx4 __attribute__((ext_vector_type(4)));
typedef __bf16 bf16x8 __attribute__((ext_vector_type(8)));
typedef unsigned short ushort_t;
typedef ushort_t ushort8 __attribute__((ext_vector_type(8)));
typedef ushort_t ushort4v __attribute__((ext_vector_type(4)));

// f32 -> bf16 bits, round-to-nearest-even
static __device__ __forceinline__ ushort_t f2bf(float x) {
  unsigned int u = __float_as_uint(x);
  return (ushort_t)((u + 0x7fffu + ((u >> 16) & 1u)) >> 16);
}
static __device__ __forceinline__ bf16x8 pack8(ushort4v lo, ushort4v hi) {
  ushort8 u;
  u[0] = lo.x; u[1] = lo.y; u[2] = lo.z; u[3] = lo.w;
  u[4] = hi.x; u[5] = hi.y; u[6] = hi.z; u[7] = hi.w;
  return __builtin_bit_cast(bf16x8, u);
}

// ---------------------------------------------------------------------------
// Kernel 1: projections -> bf16 Qb[row][d], Kb[row][d], NVT[b][d][j],
// Wtb (bf16 Wt). 256 blocks x 256 thr, 8 rows/block. Blocks 0..15 zero stats.
// ---------------------------------------------------------------------------
__global__ __launch_bounds__(256) void qkv_kernel(
    const float* __restrict__ nodes,
    const float* __restrict__ Wq, const float* __restrict__ bq,
    const float* __restrict__ Wk, const float* __restrict__ bk,
    const float* __restrict__ Wnv, const float* __restrict__ bnv,
    const float* __restrict__ Wt,
    ushort_t* __restrict__ Qb, ushort_t* __restrict__ Kb,
    ushort_t* __restrict__ NVT, ushort_t* __restrict__ Wtb,
    float* __restrict__ stats) {
  const int tid = threadIdx.x;
  const int blk = blockIdx.x;           // 0..255
  const int rowbase = blk * 8;
  const int b = rowbase >> 9;
  const int jloc = rowbase & (NNODE - 1);
  if (blk < 2 * NSTATBUF) stats[blk * 256 + tid] = 0.f;   // 16x256 = 4096
  {  // Wt -> bf16: 40960 elems, 160 per block
    const int base = blk * 160;
    if (tid < 160) Wtb[base + tid] = f2bf(Wt[base + tid]);
  }
  __shared__ float sn[RPB][NFEAT];
  if (tid < RPB * NFEAT) ((float*)sn)[tid] = nodes[(size_t)rowbase * NFEAT + tid];
  __syncthreads();

  // ---- Q/K: thread owns d = tid&127; rows (tid>>7)*4 .. +3 --------------
  {
    const int d  = tid & 127;
    const int rg = tid >> 7;
    float wq[NFEAT], wk[NFEAT];
#pragma unroll
    for (int k = 0; k < NFEAT; ++k) {
      wq[k] = Wq[d * NFEAT + k];
      wk[k] = Wk[d * NFEAT + k];
    }
    const float bqv = bq[d], bkv = bk[d];
#pragma unroll
    for (int rr = 0; rr < 4; ++rr) {
      const int rl = rg * 4 + rr;
      float aq = bqv, ak = bkv;
#pragma unroll
      for (int k = 0; k < NFEAT; ++k) {
        const float n = sn[rl][k];
        aq = fmaf(n, wq[k], aq);
        ak = fmaf(n, wk[k], ak);
      }
      Qb[(size_t)(rowbase + rl) * QKD + d] = f2bf(aq);
      Kb[(size_t)(rowbase + rl) * QKD + d] = f2bf(ak);
    }
  }
  // ---- NV^T: thread owns d = tid>>1, half = tid&1 (4 j each) ------------
  {
    const int d    = tid >> 1;
    const int half = tid & 1;
    float wnv[NFEAT];
#pragma unroll
    for (int k = 0; k < NFEAT; ++k) wnv[k] = Wnv[d * NFEAT + k];
    const float bnvv = bnv[d];
    ushort4v v;
#pragma unroll
    for (int e = 0; e < 4; ++e) {
      const int rl = half * 4 + e;
      float av = bnvv;
#pragma unroll
      for (int k = 0; k < NFEAT; ++k) av = fmaf(sn[rl][k], wnv[k], av);
      v[e] = f2bf(av);
    }
    *(ushort4v*)(NVT + (size_t)b * QKD * NNODE + (size_t)d * NNODE +
                 jloc + half * 4) = v;
  }
}

// ---------------------------------------------------------------------------
// Kernel 2: attnTrans — flash attention (online softmax over 4 chunks) fused
// with the tanh+transform MFMA and BN-stat atomics.
// 256 blocks (1/CU) x 512 thr (8 waves); block = 8 query rows x all 512 j.
// Fragment layout (16x16x32 bf16), verified R5:
//   A: lane l -> row=l&15, k=4*(l>>4)+{0..3}, elems 4..7 at k+16
//   B: lane l -> col=l&15, same k pattern
//   C: lane l, reg r -> col=l&15, row=(l>>4)*4+r
// Garbage rows 8..15 (half-empty M) are contained: D-row i depends only on
// A-row i and C-row i; outputs for rows>=8 are never written.
// ---------------------------------------------------------------------------
__global__ __launch_bounds__(512) void attnTrans_kernel(
    const ushort_t* __restrict__ Qb, const ushort_t* __restrict__ Kb,
    const ushort_t* __restrict__ NVT,
    const float* __restrict__ edges, const float* __restrict__ dist,
    const int* __restrict__ mask,
    const float* __restrict__ Wev, const float* __restrict__ bev,
    const ushort_t* __restrict__ Wtb, const float* __restrict__ bt,
    float* __restrict__ vals, float* __restrict__ stats) {
  __shared__ ushort_t sKB[JC * KBW];          // 34.8 KB
  __shared__ ushort_t sNV[2][QKD * KBW];      // 69.6 KB (double-buffered)
  __shared__ __align__(16) float sS[16][SSW]; // 8.4 KB (scores -> w)
  __shared__ ushort_t catb[RPB * CATB];       // 2.7 KB
  __shared__ float sF[16], sF2[RPB], sSe[RPB], sSw[RPB];

  const int tid = threadIdx.x;
  const int bid = blockIdx.x;            // 0..255
  const int b   = bid >> 6;              // batch
  const int rg  = bid & 63;              // row group
  const int rowbase = b * NNODE + rg * RPB;

  const int lane = tid & 63;
  const int wv   = tid >> 6;             // wave 0..7
  const int col  = lane & 15;
  const int kg   = lane >> 4;

  if (tid < 16) sF[tid] = 0.f;           // rows 8..15 stay 0 forever

  // ---- Q A-fragments (rows constant across chunks) ----------------------
  bf16x8 aq[4];
  {
    const ushort_t* Qr = Qb + (size_t)(rowbase + (col & 7)) * QKD;
#pragma unroll
    for (int ks = 0; ks < 4; ++ks)
      aq[ks] = pack8(*(const ushort4v*)(Qr + ks * 32 + kg * 4),
                     *(const ushort4v*)(Qr + ks * 32 + 16 + kg * 4));
  }

  const int sd   = tid >> 2;             // staging row 0..127
  const int sseg = (tid & 3) * 32;       // 32-ushort segment
  const int jl   = wv * 16 + col;        // this thread's chunk-local j (QK^T)
  const int dpv  = wv * 16 + col;        // this thread's d column (PV)

  float m_run = -__builtin_inff(), l_run = 0.f, se_run = 0.f;  // row = wv
  floatx4 acc = {0.f, 0.f, 0.f, 0.f};    // PV accumulator (rows kg*4+r, col dpv)
  const float coeff = 0.0883883476483184f;  // 1/sqrt(128)

  for (int c = 0; c < NCHUNK; ++c) {
    const int jbase = c * JC;
    // ---- prefetch dist/mask (score positions) + edges (softmax row wv) --
    float dd[4]; int mm[4];
#pragma unroll
    for (int r = 0; r < 4; ++r) {
      const size_t off =
          (size_t)(rowbase + ((kg * 4 + r) & 7)) * NNODE + jbase + jl;
      dd[r] = dist[off];
      mm[r] = mask[off];
    }
    const float e0 = edges[(size_t)(rowbase + wv) * NNODE + jbase + lane];
    const float e1 = edges[(size_t)(rowbase + wv) * NNODE + jbase + 64 + lane];

    // ---- stage K chunk -> sKB, NV chunk -> sNV[c&1] ---------------------
    {
      const ushort8* ksrc =
          (const ushort8*)(Kb + (size_t)(b * NNODE + jbase + sd) * QKD + sseg);
      ushort8* kdst = (ushort8*)(sKB + sd * KBW + sseg);
#pragma unroll
      for (int t = 0; t < 4; ++t) kdst[t] = ksrc[t];
      const ushort8* nsrc = (const ushort8*)(NVT + (size_t)b * QKD * NNODE +
                                             (size_t)sd * NNODE + jbase + sseg);
      ushort8* ndst = (ushort8*)(sNV[c & 1] + sd * KBW + sseg);
#pragma unroll
      for (int t = 0; t < 4; ++t) ndst[t] = nsrc[t];
    }
    __syncthreads();

    // ---- QK^T: wave owns j-tile wv; 4 MFMAs -----------------------------
    {
      floatx4 sc = {0.f, 0.f, 0.f, 0.f};
      const ushort_t* kb = sKB + (size_t)jl * KBW;
#pragma unroll
      for (int ks = 0; ks < 4; ++ks) {
        const bf16x8 bfk = pack8(*(const ushort4v*)(kb + ks * 32 + kg * 4),
                                 *(const ushort4v*)(kb + ks * 32 + 16 + kg * 4));
        sc = __builtin_amdgcn_mfma_f32_16x16x32_bf16(aq[ks], bfk, sc, 0, 0, 0);
      }
#pragma unroll
      for (int r = 0; r < 4; ++r) {
        float s = sc[r] * coeff / (dd[r] + 1.0f);
        if (mm[r]) s = -__builtin_inff();
        sS[kg * 4 + r][jl] = s;
      }
    }
    __syncthreads();

    // ---- online softmax: wave wv owns row wv ----------------------------
    {
      const float v0 = sS[wv][lane];
      const float v1 = sS[wv][lane + 64];
      float mc = fmaxf(v0, v1);
#pragma unroll
      for (int s = 1; s < 64; s <<= 1) mc = fmaxf(mc, __shfl_xor(mc, s, 64));
      const float mn = fmaxf(m_run, mc);
      const float f = (m_run > -__builtin_inff()) ? __expf(m_run - mn) : 0.f;
      float w0 = 0.f, w1 = 0.f;
      if (mn > -__builtin_inff()) {      // wave-uniform
        w0 = __expf(v0 - mn);
        w1 = __expf(v1 - mn);
      }
      sS[wv][lane]      = w0;
      sS[wv][lane + 64] = w1;
      float lc = w0 + w1;
      float sec = fmaf(w0, e0, w1 * e1);
#pragma unroll
      for (int s = 1; s < 64; s <<= 1) {
        lc  += __shfl_xor(lc, s, 64);
        sec += __shfl_xor(sec, s, 64);
      }
      l_run  = l_run * f + lc;
      se_run = se_run * f + sec;
      m_run  = mn;
      if (lane == 0) sF[wv] = f;
    }
    __syncthreads();

    // ---- PV: rescale acc, then acc += w(16x128) @ NV(128x d-tile) -------
    {
      acc[0] *= sF[kg * 4 + 0];
      acc[1] *= sF[kg * 4 + 1];
      acc[2] *= sF[kg * 4 + 2];
      acc[3] *= sF[kg * 4 + 3];
      const ushort_t* nv = sNV[c & 1] + (size_t)dpv * KBW;
#pragma unroll
      for (int ks = 0; ks < 4; ++ks) {
        const float4 lo = *(const float4*)&sS[col][ks * 32 + kg * 4];
        const float4 hi = *(const float4*)&sS[col][ks * 32 + 16 + kg * 4];
        ushort8 u;
        u[0] = f2bf(lo.x); u[1] = f2bf(lo.y); u[2] = f2bf(lo.z); u[3] = f2bf(lo.w);
        u[4] = f2bf(hi.x); u[5] = f2bf(hi.y); u[6] = f2bf(hi.z); u[7] = f2bf(hi.w);
        const bf16x8 aw = __builtin_bit_cast(bf16x8, u);
        const bf16x8 bnv = pack8(*(const ushort4v*)(nv + ks * 32 + kg * 4),
                                 *(const ushort4v*)(nv + ks * 32 + 16 + kg * 4));
        acc = __builtin_amdgcn_mfma_f32_16x16x32_bf16(aw, bnv, acc, 0, 0, 0);
      }
    }
    // no loop-bottom barrier needed: next K-stage doesn't touch sNV[c&1]/sS,
    // next NV-stage targets the other buffer, and next sS writes are after
    // the next barrier (all waves have finished PV by then).
  }

  // ---- epilogue: finalize row stats -------------------------------------
  {
    const float inv = (l_run > 0.f) ? 1.f / l_run : 0.f;
    if (lane == 0) {
      sF2[wv] = inv;
      sSe[wv] = se_run * inv;
      sSw[wv] = (l_run > 0.f) ? 1.f : 0.f;
    }
  }
  __syncthreads();

  // ---- normalize + tanh -> catb (bf16) ----------------------------------
  if (kg < 2) {
#pragma unroll
    for (int r = 0; r < 4; ++r) {
      const int row = kg * 4 + r;
      catb[row * CATB + dpv] = f2bf(tanhf(acc[r] * sF2[row]));
    }
  }
  if (tid < RPB * EVD) {                 // 256 edge elems
    const int r = tid >> 5, de = tid & 31;
    catb[r * CATB + NVD + de] =
        f2bf(tanhf(fmaf(Wev[de], sSe[r], bev[de] * sSw[r])));
  }
  __syncthreads();

  // ---- transform: vals = catb @ Wtb^T + bt; BN stat atomics --------------
  {
    bf16x8 af[5];
    const ushort_t* cr = catb + (size_t)(col & 7) * CATB;
#pragma unroll
    for (int ks = 0; ks < 5; ++ks)
      af[ks] = pack8(*(const ushort4v*)(cr + ks * 32 + kg * 4),
                     *(const ushort4v*)(cr + ks * 32 + 16 + kg * 4));
    float* sbuf = stats + (size_t)(bid & (NSTATBUF - 1)) * 2 * TRD;
#pragma unroll
    for (int t = 0; t < 2; ++t) {        // 16 col-tiles / 8 waves
      const int o = (wv * 2 + t) * 16 + col;
      const ushort_t* wr = Wtb + (size_t)o * CATD;
      floatx4 a2 = {0.f, 0.f, 0.f, 0.f};
#pragma unroll
      for (int ks = 0; ks < 5; ++ks) {
        const bf16x8 bf = pack8(*(const ushort4v*)(wr + ks * 32 + kg * 4),
                                *(const ushort4v*)(wr + ks * 32 + 16 + kg * 4));
        a2 = __builtin_amdgcn_mfma_f32_16x16x32_bf16(af[ks], bf, a2, 0, 0, 0);
      }
      const float bto = bt[o];
      float s1 = 0.f, s2 = 0.f;
#pragma unroll
      for (int r = 0; r < 4; ++r) {
        const float v2 = a2[r] + bto;
        if (kg < 2) {
          vals[(size_t)(rowbase + kg * 4 + r) * TRD + o] = v2;
          s1 += v2;
          s2 = fmaf(v2, v2, s2);
        }
      }
      s1 += __shfl_xor(s1, 16, 64); s2 += __shfl_xor(s2, 16, 64);
      s1 += __shfl_xor(s1, 32, 64); s2 += __shfl_xor(s2, 32, 64);
      if (kg == 0) {
        atomicAdd(&sbuf[o], s1);
        atomicAdd(&sbuf[TRD + o], s2);
      }
    }
  }
}

// ---------------------------------------------------------------------------
// Kernel 3: fused BN-fold + classifier. 512 blocks x 256 thr, 4 rows/block.
// ---------------------------------------------------------------------------
__global__ __launch_bounds__(256) void outbn_kernel(
    const float* __restrict__ vals, const float* __restrict__ stats,
    const float* __restrict__ gamma, const float* __restrict__ beta,
    const float* __restrict__ Wc, const float* __restrict__ bc,
    float* __restrict__ out) {
  __shared__ float sW[NCLS][TRD];
  __shared__ float sb[NCLS];
  __shared__ float red[4][NCLS];
  const int tid = threadIdx.x;
  const int o = tid;                   // 0..255
  float s1 = 0.f, s2 = 0.f;
#pragma unroll
  for (int k = 0; k < NSTATBUF; ++k) {
    s1 += stats[k * 2 * TRD + o];
    s2 += stats[k * 2 * TRD + TRD + o];
  }
  const float invN = 1.0f / (float)NROWS;
  const float mu  = s1 * invN;
  const float var = s2 * invN - mu * mu;
  const float inv = 1.0f / sqrtf(var + EPSV);
  const float g = gamma[o] * inv;
  const float bterm = beta[o] - mu * g;
  float v[NCLS];
#pragma unroll
  for (int c = 0; c < NCLS; ++c) {
    const float wc = Wc[c * TRD + o];
    sW[c][o] = wc * g;
    v[c] = wc * bterm;
  }
#pragma unroll
  for (int s = 1; s < 64; s <<= 1) {
#pragma unroll
    for (int c = 0; c < NCLS; ++c) v[c] += __shfl_xor(v[c], s, 64);
  }
  if ((tid & 63) == 0) {
#pragma unroll
    for (int c = 0; c < NCLS; ++c) red[tid >> 6][c] = v[c];
  }
  __syncthreads();
  if (tid < NCLS)
    sb[tid] = bc[tid] + red[0][tid] + red[1][tid] + red[2][tid] + red[3][tid];
  __syncthreads();

  const int lane = tid & 63;
  const int row = blockIdx.x * 4 + (tid >> 6);
  float vv[TRD / 64];
#pragma unroll
  for (int t = 0; t < TRD / 64; ++t)
    vv[t] = vals[(size_t)row * TRD + lane + 64 * t];
#pragma unroll
  for (int c = 0; c < NCLS; ++c) {
    float p = 0.f;
#pragma unroll
    for (int t = 0; t < TRD / 64; ++t)
      p = fmaf(vv[t], sW[c][lane + 64 * t], p);
#pragma unroll
    for (int s = 1; s < 64; s <<= 1) p += __shfl_xor(p, s, 64);
    if (lane == 0) out[(size_t)row * NCLS + c] = p + sb[c];
  }
}

// ---------------------------------------------------------------------------
extern "C" void kernel_launch(void* const* d_in, const int* in_sizes, int n_in,
                              void* d_out, int out_size, void* d_ws, size_t ws_size,
                              hipStream_t stream) {
  (void)in_sizes; (void)n_in; (void)out_size; (void)ws_size;
  const float* nodes = (const float*)d_in[0];
  const float* edges = (const float*)d_in[1];
  const float* dist  = (const float*)d_in[2];
  const int*   mask  = (const int*)d_in[3];
  const float* Wq  = (const float*)d_in[4];
  const float* bq  = (const float*)d_in[5];
  const float* Wk  = (const float*)d_in[6];
  const float* bk  = (const float*)d_in[7];
  const float* Wnv = (const float*)d_in[8];
  const float* bnv = (const float*)d_in[9];
  const float* Wev = (const float*)d_in[10];
  const float* bev = (const float*)d_in[11];
  const float* Wt  = (const float*)d_in[12];
  const float* bt  = (const float*)d_in[13];
  const float* gamma = (const float*)d_in[14];
  const float* beta  = (const float*)d_in[15];
  const float* Wc  = (const float*)d_in[16];
  const float* bc  = (const float*)d_in[17];

  char* w = (char*)d_ws;
  ushort_t* Qb  = (ushort_t*)w;                      w += (size_t)NROWS * QKD * 2;
  ushort_t* Kb  = (ushort_t*)w;                      w += (size_t)NROWS * QKD * 2;
  ushort_t* NVT = (ushort_t*)w;                      w += (size_t)NBATCH * QKD * NNODE * 2;
  ushort_t* Wtb = (ushort_t*)w;                      w += (size_t)TRD * CATD * 2;
  float* vals  = (float*)w;                          w += (size_t)NROWS * TRD * 4;
  float* stats = (float*)w;
  float* outp  = (float*)d_out;

  qkv_kernel<<<NROWS / RPB, 256, 0, stream>>>(nodes, Wq, bq, Wk, bk, Wnv, bnv,
                                              Wt, Qb, Kb, NVT, Wtb, stats);
  attnTrans_kernel<<<NROWS / RPB, 512, 0, stream>>>(
      Qb, Kb, NVT, edges, dist, mask, Wev, bev, Wtb, bt, vals, stats);
  outbn_kernel<<<NROWS / 4, 256, 0, stream>>>(vals, stats, gamma, beta,
                                              Wc, bc, outp);
}